// Round 11
// baseline (170.635 us; speedup 1.0000x reference)
//
#include <hip/hip_runtime.h>

// BitDelta chained layers: per layer W = base + bd*mask (4096x4096 fp32),
// x = x @ W, x [16,4096].  Weight-streaming, memory-bound (134 MB/layer).
//
// R11 = R10's wave-level decomposition EXACTLY (4096 waves, each streams
// KW=16 k-rows x 256 cols, float4 granule, depth-1 window prefetch,
// scalar-x), regrouped as 256 blocks x 16 waves (TPB=1024, 1 block/CU,
// 16 waves/CU) so each block spans KC=256 k-rows -> KCHUNKS=16 slabs:
// partial traffic drops 16->4 MB/layer, reduce reads 16.25->4.06 MB.
// Intra-block 16-way reduce: level 1 = 4 parallel quad-reduces (R10's
// proven 12 KB pattern x4 = 48 KB), level 2 = 4-way over quad leaders.
// Stage 2: 256 blocks x 64 threads fold the 16 k-partials into output.

#define DD 4096
#define BB 16
#define KW 16                  // k-rows per wave (unchanged from R10)
#define NW 16                  // waves per block
#define KC (KW * NW)           // 256 k-rows per block
#define VEC 4
#define CT 256                 // cols per block (64 lanes * 4)
#define TPB 1024               // 16 waves
#define KCHUNKS (DD / KC)      // 16
#define NCHUNKS (DD / CT)      // 16
#define OUT_ELEMS (BB * DD)    // 65536

typedef float f32x4 __attribute__((ext_vector_type(4)));

__global__ __launch_bounds__(TPB)
void bitdelta_layer(const float* __restrict__ x,
                    const float* __restrict__ base,
                    const float* __restrict__ mask,
                    const float* __restrict__ bitdelta,
                    int layer,
                    float* __restrict__ part) {
    __shared__ float red[4][16][192];   // 48 KB: per-quad R10 reduce buffers

    const int tid = threadIdx.x;
    const int l   = tid & 63;
    const int wid = __builtin_amdgcn_readfirstlane(tid >> 6);  // 0..15

    const int bid    = blockIdx.x;
    const int cchunk = bid & (NCHUNKS - 1);
    const int kchunk = bid >> 4;              // bid / NCHUNKS

    const int c0 = cchunk * CT + l * VEC;
    const int k0 = kchunk * KC + wid * KW;    // wave-uniform

    const float bd = bitdelta[layer];

    const float* wb = base + (size_t)k0 * DD + c0;
    const float* wm = mask + (size_t)k0 * DD + c0;
    const float* xp = x + k0;                 // wave-uniform base

    float acc[BB][VEC];
#pragma unroll
    for (int r = 0; r < BB; ++r)
#pragma unroll
        for (int c = 0; c < VEC; ++c) acc[r][c] = 0.0f;

    // ---- streaming k-loop: BYTE-IDENTICAL pattern to R10 ----
    float4 b0 = *reinterpret_cast<const float4*>(wb);
    float4 b1 = *reinterpret_cast<const float4*>(wb + DD);
    float4 m0 = *reinterpret_cast<const float4*>(wm);
    float4 m1 = *reinterpret_cast<const float4*>(wm + DD);

#pragma unroll
    for (int kw = 0; kw < KW; kw += 2) {
        float4 nb0, nb1, nm0, nm1;
        if (kw + 2 < KW) {   // compile-time after full unroll
            const float* pb = wb + (size_t)(kw + 2) * DD;
            const float* pm = wm + (size_t)(kw + 2) * DD;
            nb0 = *reinterpret_cast<const float4*>(pb);
            nb1 = *reinterpret_cast<const float4*>(pb + DD);
            nm0 = *reinterpret_cast<const float4*>(pm);
            nm1 = *reinterpret_cast<const float4*>(pm + DD);
        }

        const float w00 = fmaf(bd, m0.x, b0.x);
        const float w01 = fmaf(bd, m0.y, b0.y);
        const float w02 = fmaf(bd, m0.z, b0.z);
        const float w03 = fmaf(bd, m0.w, b0.w);
        const float w10 = fmaf(bd, m1.x, b1.x);
        const float w11 = fmaf(bd, m1.y, b1.y);
        const float w12 = fmaf(bd, m1.z, b1.z);
        const float w13 = fmaf(bd, m1.w, b1.w);

#pragma unroll
        for (int r = 0; r < BB; ++r) {
            const float xv0 = xp[r * DD + kw];       // wave-uniform s_load
            const float xv1 = xp[r * DD + kw + 1];
            acc[r][0] = fmaf(xv0, w00, acc[r][0]);
            acc[r][1] = fmaf(xv0, w01, acc[r][1]);
            acc[r][2] = fmaf(xv0, w02, acc[r][2]);
            acc[r][3] = fmaf(xv0, w03, acc[r][3]);
            acc[r][0] = fmaf(xv1, w10, acc[r][0]);
            acc[r][1] = fmaf(xv1, w11, acc[r][1]);
            acc[r][2] = fmaf(xv1, w12, acc[r][2]);
            acc[r][3] = fmaf(xv1, w13, acc[r][3]);
        }

        if (kw + 2 < KW) { b0 = nb0; b1 = nb1; m0 = nm0; m1 = nm1; }
    }

    // ---- level 1: four parallel 4-way quad reduces (R10 pattern) ----
    const int g   = wid >> 2;   // quad id 0..3
    const int sub = wid & 3;    // position in quad
#pragma unroll
    for (int t = 0; t < 4; ++t) {
        if (t) __syncthreads();
        if (sub != 0) {
#pragma unroll
            for (int e = 0; e < 16; ++e) {
                const int r = t * 4 + (e >> 2), c = e & 3;
                red[g][e][(sub - 1) * 64 + l] = acc[r][c];
            }
        }
        __syncthreads();
        if (sub == 0) {
#pragma unroll
            for (int e = 0; e < 16; ++e) {
                const int r = t * 4 + (e >> 2), c = e & 3;
                acc[r][c] += red[g][e][l] + red[g][e][64 + l] + red[g][e][128 + l];
            }
        }
    }
    __syncthreads();

    // ---- level 2: 4-way reduce over quad leaders (buffer reused [64][192]) ----
    float* r2 = &red[0][0][0];
    if (sub == 0 && g != 0) {
#pragma unroll
        for (int e = 0; e < 64; ++e) {
            const int r = e >> 2, c = e & 3;
            r2[e * 192 + (g - 1) * 64 + l] = acc[r][c];
        }
    }
    __syncthreads();

    if (wid == 0) {
#pragma unroll
        for (int e = 0; e < 64; ++e) {
            const int r = e >> 2, c = e & 3;
            acc[r][c] += r2[e * 192 + l] + r2[e * 192 + 64 + l] + r2[e * 192 + 128 + l];
        }
        // Block partial: [16][256] slab, float4 stores.
        float* pp = part + (size_t)kchunk * OUT_ELEMS;
#pragma unroll
        for (int r = 0; r < BB; ++r) {
            f32x4 v = { acc[r][0], acc[r][1], acc[r][2], acc[r][3] };
            *reinterpret_cast<f32x4*>(&pp[r * DD + c0]) = v;
        }
    }
}

// Stage 2: out[e] = sum_k part[k][e].  256 blocks x 64 threads: one wave
// per CU; lane owns one float4 (1 KB contiguous per slab-load); 16
// independent slab loads per thread (deep ILP).
__global__ __launch_bounds__(64)
void reduce_partials(const float* __restrict__ part, float* __restrict__ out) {
    const int idx = (blockIdx.x * 64 + threadIdx.x) * 4;   // float4 base
    f32x4 a = *reinterpret_cast<const f32x4*>(&part[idx]);
#pragma unroll
    for (int k = 1; k < KCHUNKS; ++k) {
        const f32x4 p = *reinterpret_cast<const f32x4*>(
            &part[(size_t)k * OUT_ELEMS + idx]);
        a += p;
    }
    *reinterpret_cast<f32x4*>(&out[idx]) = a;
}

extern "C" void kernel_launch(void* const* d_in, const int* in_sizes, int n_in,
                              void* d_out, int out_size, void* d_ws, size_t ws_size,
                              hipStream_t stream) {
    const float* x    = (const float*)d_in[0];   // [16,4096]
    const float* base = (const float*)d_in[1];   // [4,4096,4096]
    const float* mask = (const float*)d_in[2];   // [4,4096,4096]
    const float* bd   = (const float*)d_in[3];   // [4]
    float* out = (float*)d_out;                  // [16,4096] fp32

    float* part = (float*)d_ws;                  // 16 x 65536 floats = 4 MB
    float* y0   = part + (size_t)KCHUNKS * OUT_ELEMS;
    float* y1   = y0 + OUT_ELEMS;

    const size_t layer_stride = (size_t)DD * DD;
    const int    grid1 = KCHUNKS * NCHUNKS;      // 256 blocks x 1024 threads
    const int    grid2 = OUT_ELEMS / (64 * 4);   // 256 blocks x 64 threads

    bitdelta_layer<<<grid1, TPB, 0, stream>>>(x, base, mask, bd, 0, part);
    reduce_partials<<<grid2, 64, 0, stream>>>(part, y0);

    bitdelta_layer<<<grid1, TPB, 0, stream>>>(y0, base + 1 * layer_stride,
                                              mask + 1 * layer_stride, bd, 1, part);
    reduce_partials<<<grid2, 64, 0, stream>>>(part, y1);

    bitdelta_layer<<<grid1, TPB, 0, stream>>>(y1, base + 2 * layer_stride,
                                              mask + 2 * layer_stride, bd, 2, part);
    reduce_partials<<<grid2, 64, 0, stream>>>(part, y0);

    bitdelta_layer<<<grid1, TPB, 0, stream>>>(y0, base + 3 * layer_stride,
                                              mask + 3 * layer_stride, bd, 3, part);
    reduce_partials<<<grid2, 64, 0, stream>>>(part, out);
}